// Round 12
// baseline (197.506 us; speedup 1.0000x reference)
//
#include <hip/hip_runtime.h>

#define NBIN 256
#define RCAP 256                  // per-wave ring capacity (occupancy bound <= 127)
#define EPSF 1e-10f
#define DSCALE 4096.0f            // 2^12 fixed-point scale for fractional part
#define DSCALE_INV (1.0 / 4096.0)
#define DMASK ((1ull << 40) - 1)  // global packed: count<<40 | fracsum(2^12)

// ---- monotone float<->uint encoding for atomicMin on floats ----
__device__ __forceinline__ unsigned enc_f32(float f) {
    unsigned u = __float_as_uint(f);
    return (u & 0x80000000u) ? ~u : (u ^ 0x80000000u);
}
__device__ __forceinline__ float dec_f32(unsigned e) {
    unsigned u = (e & 0x80000000u) ? (e ^ 0x80000000u) : ~e;
    return __uint_as_float(u);
}

// ws layout: [0] = encoded running min (unsigned); u64 at byte offset 16:
//   gh[0..255]   = packed (count<<40 | dsum_fix12) for img0
//   gh[256..511] = same for img1
__global__ void init_kernel(unsigned* ws_min, unsigned long long* gh) {
    if (threadIdx.x == 0) *ws_min = 0xFFFFFFFFu;
    for (int j = threadIdx.x; j < 2 * NBIN; j += blockDim.x) gh[j] = 0ull;
}

__global__ void __launch_bounds__(256) min_kernel(const float4* __restrict__ img0,
                                                  long n4, unsigned* ws_min) {
    long stride = (long)gridDim.x * blockDim.x;
    long i = (long)blockIdx.x * blockDim.x + threadIdx.x;
    float m = __int_as_float(0x7f800000);  // +inf
    if (i < n4) {
        float4 cur = img0[i];
        long j = i + stride;
        for (; j < n4; j += stride) {
            float4 nxt = img0[j];
            m = fminf(m, fminf(fminf(cur.x, cur.y), fminf(cur.z, cur.w)));
            cur = nxt;
        }
        m = fminf(m, fminf(fminf(cur.x, cur.y), fminf(cur.z, cur.w)));
    }
    for (int off = 32; off; off >>= 1) m = fminf(m, __shfl_xor(m, off));
    __shared__ float sm[4];
    int lane = threadIdx.x & 63, wid = threadIdx.x >> 6;
    if (lane == 0) sm[wid] = m;
    __syncthreads();
    if (threadIdx.x == 0) {
        float bm = fminf(fminf(sm[0], sm[1]), fminf(sm[2], sm[3]));
        atomicMin(ws_min, enc_f32(bm));
    }
}

// Wave-shared LDS ring: kept entries are compacted (ballot + mbcnt rank) into
// consecutive ring slots (conflict-free ds_write). When >=64 entries are
// buffered (WAVE-UNIFORM scalar test -- no 64-lane ANY amplification), all 64
// lanes pop one entry and issue ONE fully-packed atomic. Atomic instruction
// count = kept/64 exactly (T = 0.5/slot), the conservation floor.
__global__ void __launch_bounds__(256) hist_kernel(const float4* __restrict__ img0,
                                                   const float4* __restrict__ img1,
                                                   long n4, const unsigned* ws_min,
                                                   unsigned long long* __restrict__ gh) {
    __shared__ unsigned lh[4][2][NBIN];   // per-wave packed u32 tables, 8 KB
    __shared__ unsigned ring[4][RCAP];    // per-wave entry rings, 4 KB
    int tid = threadIdx.x;
    int wid = tid >> 6;
    int lane = tid & 63;
    unsigned* base = &lh[0][0][0];
    for (int j = tid; j < 4 * 2 * NBIN; j += 256) base[j] = 0u;
    __syncthreads();

    float hmin = dec_f32(*ws_min);
    float dh = (0.f - hmin) / (NBIN - 1);
    float inv_dh = 1.0f / dh;

    long stride = (long)gridDim.x * blockDim.x;
    unsigned* tab = &lh[wid][0][0];   // flat [2][256]; offset = img*256+idx
    unsigned* rg = &ring[wid][0];

    unsigned head = 0, tail = 0;      // wave-uniform (scalar) ring pointers

    auto slot = [&](float v, int img) {
        bool keep = (v >= hmin) & (v <= 0.f);
        float x = (v - hmin) * inv_dh;
        x = fminf(fmaxf(x, 0.f), 255.f);
        float fi = floorf(x);
        int idx = (int)fi;                                   // 0..255
        unsigned di = __float2uint_rn((x - fi) * DSCALE);
        di = di > 4095u ? 4095u : di;
        unsigned entry = ((unsigned)((img << 8) | idx) << 12) | di;  // 21 bits

        unsigned long long mask = __ballot(keep);
        unsigned rank = __builtin_amdgcn_mbcnt_hi(
            (unsigned)(mask >> 32), __builtin_amdgcn_mbcnt_lo((unsigned)mask, 0u));
        if (keep) rg[(tail + rank) & (RCAP - 1)] = entry;    // compacted write
        tail += (unsigned)__popcll(mask);                    // uniform
        if (tail - head >= 64u) {                            // uniform branch
            unsigned e = rg[(head + lane) & (RCAP - 1)];
            atomicAdd(&tab[e >> 12], (1u << 24) | (e & 0xFFFu));
            head += 64u;
        }
    };

    long i = (long)blockIdx.x * blockDim.x + tid;
    if (i < n4) {
        float4 a = img0[i];
        float4 b = img1[i];
        long j = i + stride;
        for (; j < n4; j += stride) {
            float4 an = img0[j];
            float4 bn = img1[j];
            slot(a.x, 0); slot(a.y, 0); slot(a.z, 0); slot(a.w, 0);
            slot(b.x, 1); slot(b.y, 1); slot(b.z, 1); slot(b.w, 1);
            a = an;
            b = bn;
        }
        slot(a.x, 0); slot(a.y, 0); slot(a.z, 0); slot(a.w, 0);
        slot(b.x, 1); slot(b.y, 1); slot(b.z, 1); slot(b.w, 1);
    }
    // drain the ring (occupancy <= 127 -> at most 2 partial batches)
    {
        unsigned rem = tail - head;
        if (lane < (int)rem) {
            unsigned e = rg[(head + lane) & (RCAP - 1)];
            atomicAdd(&tab[e >> 12], (1u << 24) | (e & 0xFFFu));
        }
        if (rem > 64u) {
            unsigned r2 = rem - 64u;
            if (lane < (int)r2) {
                unsigned e = rg[(head + 64u + lane) & (RCAP - 1)];
                atomicAdd(&tab[e >> 12], (1u << 24) | (e & 0xFFFu));
            }
        }
    }
    __syncthreads();

    // merge the 4 wave copies (exact integer adds), one global u64 atomic per bin
    for (int b = tid; b < NBIN; b += 256) {
        unsigned long long c0 = 0, f0 = 0, c1 = 0, f1 = 0;
        for (int w = 0; w < 4; ++w) {
            unsigned p0 = lh[w][0][b];
            unsigned p1 = lh[w][1][b];
            c0 += p0 >> 24; f0 += p0 & 0xFFFFFFu;
            c1 += p1 >> 24; f1 += p1 & 0xFFFFFFu;
        }
        atomicAdd(&gh[b], (c0 << 40) | f0);
        atomicAdd(&gh[NBIN + b], (c1 << 40) | f1);
    }
}

__global__ void __launch_bounds__(256) kl_kernel(const unsigned long long* __restrict__ gh,
                                                 float* __restrict__ out) {
    int i = threadIdx.x;  // exactly 256 threads, one bin each
    // unpack: h[b] = count[b] - dsum[b] + dsum[b-1]   (spill past 255 drops out)
    unsigned long long p0 = gh[i];
    unsigned long long p1 = gh[NBIN + i];
    unsigned long long q0 = (i > 0) ? gh[i - 1] : 0ull;
    unsigned long long q1 = (i > 0) ? gh[NBIN + i - 1] : 0ull;
    float h0 = (float)((double)(p0 >> 40) - (double)(p0 & DMASK) * DSCALE_INV
                       + (double)(q0 & DMASK) * DSCALE_INV);
    float h1 = (float)((double)(p1 >> 40) - (double)(p1 & DMASK) * DSCALE_INV
                       + (double)(q1 & DMASK) * DSCALE_INV);

    __shared__ float sw[4];
    int lane = i & 63, wid = i >> 6;

    float v = h0;
    for (int off = 32; off; off >>= 1) v += __shfl_xor(v, off);
    if (lane == 0) sw[wid] = v;
    __syncthreads();
    float s0 = sw[0] + sw[1] + sw[2] + sw[3];
    __syncthreads();

    v = h1;
    for (int off = 32; off; off >>= 1) v += __shfl_xor(v, off);
    if (lane == 0) sw[wid] = v;
    __syncthreads();
    float s1 = sw[0] + sw[1] + sw[2] + sw[3];
    __syncthreads();

    float a = (h0 + EPSF) / (s0 + EPSF);
    float b = (h1 + EPSF) / (s1 + EPSF);
    float tgt = logf((b + EPSF) / a);
    float inp = logf((b + EPSF) / b);
    float term = expf(tgt) * (tgt - inp);

    v = term;
    for (int off = 32; off; off >>= 1) v += __shfl_xor(v, off);
    if (lane == 0) sw[wid] = v;
    __syncthreads();
    if (i == 0) out[0] = (sw[0] + sw[1] + sw[2] + sw[3]) / (float)NBIN;
}

extern "C" void kernel_launch(void* const* d_in, const int* in_sizes, int n_in,
                              void* d_out, int out_size, void* d_ws, size_t ws_size,
                              hipStream_t stream) {
    const float* img0 = (const float*)d_in[0];
    const float* img1 = (const float*)d_in[1];
    float* out = (float*)d_out;
    unsigned* ws_min = (unsigned*)d_ws;
    unsigned long long* gh = (unsigned long long*)((char*)d_ws + 16);

    long n = (long)in_sizes[0];  // 67,108,864
    long n4 = n / 4;

    init_kernel<<<1, 256, 0, stream>>>(ws_min, gh);
    min_kernel<<<2048, 256, 0, stream>>>((const float4*)img0, n4, ws_min);
    hist_kernel<<<2048, 256, 0, stream>>>((const float4*)img0, (const float4*)img1,
                                          n4, ws_min, gh);
    kl_kernel<<<1, 256, 0, stream>>>(gh, out);
}

// Round 13
// 184.688 us; speedup vs baseline: 1.0694x; 1.0694x over previous
//
#include <hip/hip_runtime.h>

#define NBIN 256
#define EPSF 1e-10f
#define DSCALE 4096.0f            // 2^12 fixed-point scale for fractional part
#define DSCALE_INV (1.0 / 4096.0)
#define DMASK ((1ull << 40) - 1)  // global packed: count<<40 | fracsum(2^12)
#define EMASK 0x1FFFFFull         // 21-bit FIFO entry mask

// ---- monotone float<->uint encoding for atomicMin on floats ----
__device__ __forceinline__ unsigned enc_f32(float f) {
    unsigned u = __float_as_uint(f);
    return (u & 0x80000000u) ? ~u : (u ^ 0x80000000u);
}
__device__ __forceinline__ float dec_f32(unsigned e) {
    unsigned u = (e & 0x80000000u) ? (e ^ 0x80000000u) : ~e;
    return __uint_as_float(u);
}

// ws layout: [0] = encoded running min (unsigned); u64 at byte offset 16:
//   gh[0..255]   = packed (count<<40 | dsum_fix12) for img0
//   gh[256..511] = same for img1
__global__ void init_kernel(unsigned* ws_min, unsigned long long* gh) {
    if (threadIdx.x == 0) *ws_min = 0xFFFFFFFFu;
    for (int j = threadIdx.x; j < 2 * NBIN; j += blockDim.x) gh[j] = 0ull;
}

__global__ void __launch_bounds__(256) min_kernel(const float4* __restrict__ img0,
                                                  long n4, unsigned* ws_min) {
    long stride = (long)gridDim.x * blockDim.x;
    long i = (long)blockIdx.x * blockDim.x + threadIdx.x;
    float m = __int_as_float(0x7f800000);  // +inf
    if (i < n4) {
        float4 cur = img0[i];
        long j = i + stride;
        for (; j < n4; j += stride) {
            float4 nxt = img0[j];
            m = fminf(m, fminf(fminf(cur.x, cur.y), fminf(cur.z, cur.w)));
            cur = nxt;
        }
        m = fminf(m, fminf(fminf(cur.x, cur.y), fminf(cur.z, cur.w)));
    }
    for (int off = 32; off; off >>= 1) m = fminf(m, __shfl_xor(m, off));
    __shared__ float sm[4];
    int lane = threadIdx.x & 63, wid = threadIdx.x >> 6;
    if (lane == 0) sm[wid] = m;
    __syncthreads();
    if (threadIdx.x == 0) {
        float bm = fminf(fminf(sm[0], sm[1]), fminf(sm[2], sm[3]));
        atomicMin(ws_min, enc_f32(bm));
    }
}

// Depth-6 per-lane FIFO (two u64 shift registers, 3 x 21-bit entries each).
// Cost model (rounds 4/9/12 fit): time = 43cyc x atomic_instrs + ~14cyc x
// aux DS instrs. So aggregation must add ZERO aux DS ops -> register FIFO.
// Queueing lesson (r11): pops at exactly the fill rate waste on empty lanes,
// queues pile at cap, and the 64-lane ANY-pressure ballot fires ~0.4/slot.
// Fix: pop rate ABOVE fill rate (5 of 8 slots = 0.625 vs fill 0.5) so queues
// hover near empty and pressure ~never fires; T ~= 0.625 by construction.
__device__ __forceinline__ void fifo_pop(unsigned* tab, int lane,
                                         unsigned long long& qh,
                                         unsigned long long& ql, int& cnt) {
    bool has = cnt > 0;
    int pos = has ? cnt - 1 : 0;            // oldest entry position
    bool hi = pos >= 3;
    int sh = 21 * (hi ? pos - 3 : pos);
    unsigned long long src = hi ? qh : ql;
    unsigned e = (unsigned)((src >> sh) & EMASK);
    unsigned off = has ? (e >> 12) : (unsigned)lane;   // dummy: pv=0 at [lane]
    unsigned pv = has ? ((1u << 24) | (e & 0xFFFu)) : 0u;
    atomicAdd(&tab[off], pv);
    cnt -= has ? 1 : 0;
}

template <bool POPNOW>
__device__ __forceinline__ void slot(float v, float hmin, float inv_dh, int img,
                                     unsigned* tab, int lane,
                                     unsigned long long& qh,
                                     unsigned long long& ql, int& cnt) {
    bool keep = (v >= hmin) & (v <= 0.f);
    float x = (v - hmin) * inv_dh;
    x = fminf(fmaxf(x, 0.f), 255.f);
    float fi = floorf(x);
    int idx = (int)fi;                                   // 0..255
    unsigned di = __float2uint_rn((x - fi) * DSCALE);
    di = di > 4095u ? 4095u : di;                        // keep frac in 12 bits
    unsigned entry = ((unsigned)((img << 8) | idx) << 12) | di;  // 21 bits

    bool dopop;
    if (POPNOW) {
        dopop = true;                                    // fixed schedule: no ballot
    } else {
        dopop = __ballot(keep & (cnt == 6)) != 0ull;     // rare overflow pressure
    }
    if (dopop) fifo_pop(tab, lane, qh, ql, cnt);
    // push (only if keep); mask the cross-word carry to exactly 21 bits
    unsigned long long nqh = (qh << 21) | ((ql >> 42) & EMASK);
    unsigned long long nql = (ql << 21) | (unsigned long long)entry;
    qh = keep ? nqh : qh;
    ql = keep ? nql : ql;
    cnt += keep ? 1 : 0;
}

__global__ void __launch_bounds__(256) hist_kernel(const float4* __restrict__ img0,
                                                   const float4* __restrict__ img1,
                                                   long n4, const unsigned* ws_min,
                                                   unsigned long long* __restrict__ gh) {
    // per-wave privatized packed u32 tables: 4 waves x 2 images x 256 bins = 8 KB
    __shared__ unsigned lh[4][2][NBIN];
    int tid = threadIdx.x;
    int wid = tid >> 6;
    int lane = tid & 63;
    unsigned* base = &lh[0][0][0];
    for (int j = tid; j < 4 * 2 * NBIN; j += 256) base[j] = 0u;
    __syncthreads();

    float hmin = dec_f32(*ws_min);
    float dh = (0.f - hmin) / (NBIN - 1);
    float inv_dh = 1.0f / dh;

    long stride = (long)gridDim.x * blockDim.x;
    unsigned* tab = &lh[wid][0][0];   // flat [2][256]; entry off = img*256+idx

    unsigned long long qh = 0ull, ql = 0ull;
    int cnt = 0;

    long i = (long)blockIdx.x * blockDim.x + tid;
    if (i < n4) {
        float4 a = img0[i];
        float4 b = img1[i];
        long j = i + stride;
        for (; j < n4; j += stride) {
            float4 an = img0[j];
            float4 bn = img1[j];
            // pop schedule: 5 of 8 slots (rate 0.625 > fill 0.5)
            slot<false>(a.x, hmin, inv_dh, 0, tab, lane, qh, ql, cnt);
            slot<true >(a.y, hmin, inv_dh, 0, tab, lane, qh, ql, cnt);
            slot<false>(a.z, hmin, inv_dh, 0, tab, lane, qh, ql, cnt);
            slot<true >(a.w, hmin, inv_dh, 0, tab, lane, qh, ql, cnt);
            slot<true >(b.x, hmin, inv_dh, 1, tab, lane, qh, ql, cnt);
            slot<false>(b.y, hmin, inv_dh, 1, tab, lane, qh, ql, cnt);
            slot<true >(b.z, hmin, inv_dh, 1, tab, lane, qh, ql, cnt);
            slot<true >(b.w, hmin, inv_dh, 1, tab, lane, qh, ql, cnt);
            a = an;
            b = bn;
        }
        slot<false>(a.x, hmin, inv_dh, 0, tab, lane, qh, ql, cnt);
        slot<true >(a.y, hmin, inv_dh, 0, tab, lane, qh, ql, cnt);
        slot<false>(a.z, hmin, inv_dh, 0, tab, lane, qh, ql, cnt);
        slot<true >(a.w, hmin, inv_dh, 0, tab, lane, qh, ql, cnt);
        slot<true >(b.x, hmin, inv_dh, 1, tab, lane, qh, ql, cnt);
        slot<false>(b.y, hmin, inv_dh, 1, tab, lane, qh, ql, cnt);
        slot<true >(b.z, hmin, inv_dh, 1, tab, lane, qh, ql, cnt);
        slot<true >(b.w, hmin, inv_dh, 1, tab, lane, qh, ql, cnt);
    }
    // drain remaining buffered entries (depth <= 6)
    for (int k = 0; k < 6; ++k) fifo_pop(tab, lane, qh, ql, cnt);
    __syncthreads();

    // merge the 4 wave copies (exact integer adds), one global u64 atomic per bin
    for (int b = tid; b < NBIN; b += 256) {
        unsigned long long c0 = 0, f0 = 0, c1 = 0, f1 = 0;
        for (int w = 0; w < 4; ++w) {
            unsigned p0 = lh[w][0][b];
            unsigned p1 = lh[w][1][b];
            c0 += p0 >> 24; f0 += p0 & 0xFFFFFFu;
            c1 += p1 >> 24; f1 += p1 & 0xFFFFFFu;
        }
        atomicAdd(&gh[b], (c0 << 40) | f0);
        atomicAdd(&gh[NBIN + b], (c1 << 40) | f1);
    }
}

__global__ void __launch_bounds__(256) kl_kernel(const unsigned long long* __restrict__ gh,
                                                 float* __restrict__ out) {
    int i = threadIdx.x;  // exactly 256 threads, one bin each
    // unpack: h[b] = count[b] - dsum[b] + dsum[b-1]   (spill past 255 drops out)
    unsigned long long p0 = gh[i];
    unsigned long long p1 = gh[NBIN + i];
    unsigned long long q0 = (i > 0) ? gh[i - 1] : 0ull;
    unsigned long long q1 = (i > 0) ? gh[NBIN + i - 1] : 0ull;
    float h0 = (float)((double)(p0 >> 40) - (double)(p0 & DMASK) * DSCALE_INV
                       + (double)(q0 & DMASK) * DSCALE_INV);
    float h1 = (float)((double)(p1 >> 40) - (double)(p1 & DMASK) * DSCALE_INV
                       + (double)(q1 & DMASK) * DSCALE_INV);

    __shared__ float sw[4];
    int lane = i & 63, wid = i >> 6;

    float v = h0;
    for (int off = 32; off; off >>= 1) v += __shfl_xor(v, off);
    if (lane == 0) sw[wid] = v;
    __syncthreads();
    float s0 = sw[0] + sw[1] + sw[2] + sw[3];
    __syncthreads();

    v = h1;
    for (int off = 32; off; off >>= 1) v += __shfl_xor(v, off);
    if (lane == 0) sw[wid] = v;
    __syncthreads();
    float s1 = sw[0] + sw[1] + sw[2] + sw[3];
    __syncthreads();

    float a = (h0 + EPSF) / (s0 + EPSF);
    float b = (h1 + EPSF) / (s1 + EPSF);
    float tgt = logf((b + EPSF) / a);
    float inp = logf((b + EPSF) / b);
    float term = expf(tgt) * (tgt - inp);

    v = term;
    for (int off = 32; off; off >>= 1) v += __shfl_xor(v, off);
    if (lane == 0) sw[wid] = v;
    __syncthreads();
    if (i == 0) out[0] = (sw[0] + sw[1] + sw[2] + sw[3]) / (float)NBIN;
}

extern "C" void kernel_launch(void* const* d_in, const int* in_sizes, int n_in,
                              void* d_out, int out_size, void* d_ws, size_t ws_size,
                              hipStream_t stream) {
    const float* img0 = (const float*)d_in[0];
    const float* img1 = (const float*)d_in[1];
    float* out = (float*)d_out;
    unsigned* ws_min = (unsigned*)d_ws;
    unsigned long long* gh = (unsigned long long*)((char*)d_ws + 16);

    long n = (long)in_sizes[0];  // 67,108,864
    long n4 = n / 4;

    init_kernel<<<1, 256, 0, stream>>>(ws_min, gh);
    min_kernel<<<2048, 256, 0, stream>>>((const float4*)img0, n4, ws_min);
    hist_kernel<<<2048, 256, 0, stream>>>((const float4*)img0, (const float4*)img1,
                                          n4, ws_min, gh);
    kl_kernel<<<1, 256, 0, stream>>>(gh, out);
}

// Round 14
// 183.140 us; speedup vs baseline: 1.0784x; 1.0085x over previous
//
#include <hip/hip_runtime.h>

#define NBIN 256
#define EPSF 1e-10f
#define DSCALE 4096.0f            // 2^12 fixed-point scale for fractional part
#define DSCALE_INV (1.0 / 4096.0)
#define DMASK ((1ull << 40) - 1)  // global packed: count<<40 | fracsum(2^12)
#define FULLM 0xFFFFFFFFFFFFFFFFull

// ---- monotone float<->uint encoding for atomicMin on floats ----
__device__ __forceinline__ unsigned enc_f32(float f) {
    unsigned u = __float_as_uint(f);
    return (u & 0x80000000u) ? ~u : (u ^ 0x80000000u);
}
__device__ __forceinline__ float dec_f32(unsigned e) {
    unsigned u = (e & 0x80000000u) ? (e ^ 0x80000000u) : ~e;
    return __uint_as_float(u);
}

// ws layout: [0] = encoded running min (unsigned); u64 at byte offset 16:
//   gh[0..255]   = packed (count<<40 | dsum_fix12) for img0
//   gh[256..511] = same for img1
__global__ void init_kernel(unsigned* ws_min, unsigned long long* gh) {
    if (threadIdx.x == 0) *ws_min = 0xFFFFFFFFu;
    for (int j = threadIdx.x; j < 2 * NBIN; j += blockDim.x) gh[j] = 0ull;
}

__global__ void __launch_bounds__(256) min_kernel(const float4* __restrict__ img0,
                                                  long n4, unsigned* ws_min) {
    long stride = (long)gridDim.x * blockDim.x;
    long i = (long)blockIdx.x * blockDim.x + threadIdx.x;
    float m = __int_as_float(0x7f800000);  // +inf
    if (i < n4) {
        float4 cur = img0[i];
        long j = i + stride;
        for (; j < n4; j += stride) {
            float4 nxt = img0[j];              // prefetch next iteration
            m = fminf(m, fminf(fminf(cur.x, cur.y), fminf(cur.z, cur.w)));
            cur = nxt;
        }
        m = fminf(m, fminf(fminf(cur.x, cur.y), fminf(cur.z, cur.w)));
    }
    for (int off = 32; off; off >>= 1) m = fminf(m, __shfl_xor(m, off));
    __shared__ float sm[4];
    int lane = threadIdx.x & 63, wid = threadIdx.x >> 6;
    if (lane == 0) sm[wid] = m;
    __syncthreads();
    if (threadIdx.x == 0) {
        float bm = fminf(fminf(sm[0], sm[1]), fminf(sm[2], sm[3]));
        atomicMin(ws_min, enc_f32(bm));
    }
}

// Depth-3 per-lane FIFO (one u64 shift register, 3 x 21-bit entries;
// oldest = position cnt-1). DS atomic cost is flat ~37-43 cyc per
// wave-instruction (rounds 3/4/5/8/12/13 evidence) with an effective floor at
// T ~= 0.85 issues/slot; this adaptive trigger (pop when all lanes have data
// OR a lane would overflow) empirically hits that floor (r9 = best measured).
__device__ __forceinline__ void fifo_issue(unsigned* tab, int lane,
                                           unsigned long long& q, int& cnt) {
    bool has = cnt > 0;
    int sh = has ? 21 * (cnt - 1) : 0;
    unsigned e = has ? (unsigned)((q >> sh) & 0x1FFFFFull) : 0u;
    unsigned off = has ? (e >> 12) : (unsigned)lane;  // dummy: pv=0 at bin[lane]
    unsigned pv = has ? ((1u << 24) | (e & 0xFFFu)) : 0u;
    atomicAdd(&tab[off], pv);
    cnt -= has ? 1 : 0;
}

__device__ __forceinline__ void slot(float v, float hmin, float inv_dh, int img,
                                     unsigned* tab, int lane,
                                     unsigned long long& q, int& cnt) {
    bool keep = (v >= hmin) & (v <= 0.f);
    float x = (v - hmin) * inv_dh;
    x = fminf(fmaxf(x, 0.f), 255.f);
    float fi = floorf(x);
    int idx = (int)fi;                                   // 0..255
    unsigned di = __float2uint_rn((x - fi) * DSCALE);
    di = di > 4095u ? 4095u : di;                        // keep frac in 12 bits
    unsigned entry = ((unsigned)((img << 8) | idx) << 12) | di;  // 21 bits

    bool pressure = keep && (cnt == 3);
    unsigned long long ne = __ballot(cnt > 0);
    if (__ballot(pressure) != 0ull || ne == FULLM) {
        fifo_issue(tab, lane, q, cnt);                   // pops 1 where cnt>0
    }
    q = keep ? ((q << 21) | (unsigned long long)entry) : q;
    cnt += keep ? 1 : 0;
}

__global__ void __launch_bounds__(256) hist_kernel(const float4* __restrict__ img0,
                                                   const float4* __restrict__ img1,
                                                   long n4, const unsigned* ws_min,
                                                   unsigned long long* __restrict__ gh) {
    // per-wave privatized packed u32 tables: 4 waves x 2 images x 256 bins = 8 KB
    __shared__ unsigned lh[4][2][NBIN];
    int tid = threadIdx.x;
    int wid = tid >> 6;
    int lane = tid & 63;
    unsigned* base = &lh[0][0][0];
    for (int j = tid; j < 4 * 2 * NBIN; j += 256) base[j] = 0u;
    __syncthreads();

    float hmin = dec_f32(*ws_min);
    float dh = (0.f - hmin) / (NBIN - 1);
    float inv_dh = 1.0f / dh;

    long stride = (long)gridDim.x * blockDim.x;
    unsigned* tab = &lh[wid][0][0];   // flat [2][256]; entry off = img*256+idx

    unsigned long long q = 0ull;
    int cnt = 0;

    long i = (long)blockIdx.x * blockDim.x + tid;
    if (i < n4) {
        float4 a = img0[i];
        float4 b = img1[i];
        long j = i + stride;
        for (; j < n4; j += stride) {
            float4 an = img0[j];
            float4 bn = img1[j];
            slot(a.x, hmin, inv_dh, 0, tab, lane, q, cnt);
            slot(a.y, hmin, inv_dh, 0, tab, lane, q, cnt);
            slot(a.z, hmin, inv_dh, 0, tab, lane, q, cnt);
            slot(a.w, hmin, inv_dh, 0, tab, lane, q, cnt);
            slot(b.x, hmin, inv_dh, 1, tab, lane, q, cnt);
            slot(b.y, hmin, inv_dh, 1, tab, lane, q, cnt);
            slot(b.z, hmin, inv_dh, 1, tab, lane, q, cnt);
            slot(b.w, hmin, inv_dh, 1, tab, lane, q, cnt);
            a = an;
            b = bn;
        }
        slot(a.x, hmin, inv_dh, 0, tab, lane, q, cnt);
        slot(a.y, hmin, inv_dh, 0, tab, lane, q, cnt);
        slot(a.z, hmin, inv_dh, 0, tab, lane, q, cnt);
        slot(a.w, hmin, inv_dh, 0, tab, lane, q, cnt);
        slot(b.x, hmin, inv_dh, 1, tab, lane, q, cnt);
        slot(b.y, hmin, inv_dh, 1, tab, lane, q, cnt);
        slot(b.z, hmin, inv_dh, 1, tab, lane, q, cnt);
        slot(b.w, hmin, inv_dh, 1, tab, lane, q, cnt);
    }
    // drain remaining buffered entries (depth <= 3)
    for (int k = 0; k < 3; ++k) fifo_issue(tab, lane, q, cnt);
    __syncthreads();

    // merge the 4 wave copies (exact integer adds), one global u64 atomic per bin
    for (int b = tid; b < NBIN; b += 256) {
        unsigned long long c0 = 0, f0 = 0, c1 = 0, f1 = 0;
        for (int w = 0; w < 4; ++w) {
            unsigned p0 = lh[w][0][b];
            unsigned p1 = lh[w][1][b];
            c0 += p0 >> 24; f0 += p0 & 0xFFFFFFu;
            c1 += p1 >> 24; f1 += p1 & 0xFFFFFFu;
        }
        atomicAdd(&gh[b], (c0 << 40) | f0);
        atomicAdd(&gh[NBIN + b], (c1 << 40) | f1);
    }
}

__global__ void __launch_bounds__(256) kl_kernel(const unsigned long long* __restrict__ gh,
                                                 float* __restrict__ out) {
    int i = threadIdx.x;  // exactly 256 threads, one bin each
    // unpack: h[b] = count[b] - dsum[b] + dsum[b-1]   (spill past 255 drops out)
    unsigned long long p0 = gh[i];
    unsigned long long p1 = gh[NBIN + i];
    unsigned long long q0 = (i > 0) ? gh[i - 1] : 0ull;
    unsigned long long q1 = (i > 0) ? gh[NBIN + i - 1] : 0ull;
    float h0 = (float)((double)(p0 >> 40) - (double)(p0 & DMASK) * DSCALE_INV
                       + (double)(q0 & DMASK) * DSCALE_INV);
    float h1 = (float)((double)(p1 >> 40) - (double)(p1 & DMASK) * DSCALE_INV
                       + (double)(q1 & DMASK) * DSCALE_INV);

    __shared__ float sw[4];
    int lane = i & 63, wid = i >> 6;

    float v = h0;
    for (int off = 32; off; off >>= 1) v += __shfl_xor(v, off);
    if (lane == 0) sw[wid] = v;
    __syncthreads();
    float s0 = sw[0] + sw[1] + sw[2] + sw[3];
    __syncthreads();

    v = h1;
    for (int off = 32; off; off >>= 1) v += __shfl_xor(v, off);
    if (lane == 0) sw[wid] = v;
    __syncthreads();
    float s1 = sw[0] + sw[1] + sw[2] + sw[3];
    __syncthreads();

    float a = (h0 + EPSF) / (s0 + EPSF);
    float b = (h1 + EPSF) / (s1 + EPSF);
    float tgt = logf((b + EPSF) / a);
    float inp = logf((b + EPSF) / b);
    float term = expf(tgt) * (tgt - inp);

    v = term;
    for (int off = 32; off; off >>= 1) v += __shfl_xor(v, off);
    if (lane == 0) sw[wid] = v;
    __syncthreads();
    if (i == 0) out[0] = (sw[0] + sw[1] + sw[2] + sw[3]) / (float)NBIN;
}

extern "C" void kernel_launch(void* const* d_in, const int* in_sizes, int n_in,
                              void* d_out, int out_size, void* d_ws, size_t ws_size,
                              hipStream_t stream) {
    const float* img0 = (const float*)d_in[0];
    const float* img1 = (const float*)d_in[1];
    float* out = (float*)d_out;
    unsigned* ws_min = (unsigned*)d_ws;
    unsigned long long* gh = (unsigned long long*)((char*)d_ws + 16);

    long n = (long)in_sizes[0];  // 67,108,864
    long n4 = n / 4;

    init_kernel<<<1, 256, 0, stream>>>(ws_min, gh);
    min_kernel<<<2048, 256, 0, stream>>>((const float4*)img0, n4, ws_min);
    hist_kernel<<<2048, 256, 0, stream>>>((const float4*)img0, (const float4*)img1,
                                          n4, ws_min, gh);
    kl_kernel<<<1, 256, 0, stream>>>(gh, out);
}